// Round 1
// baseline (378.273 us; speedup 1.0000x reference)
//
#include <hip/hip_runtime.h>
#include <hip/hip_bf16.h>

#define N_NODES 50000
#define N_EDGES 800000
#define C 128

// ---------------------------------------------------------------------------
// CSR build: count in-degrees, prefix-sum to offsets, fill src lists.
// ---------------------------------------------------------------------------
__global__ void k_count(const int* __restrict__ ei, int* __restrict__ count) {
    int e = blockIdx.x * 256 + threadIdx.x;
    if (e < N_EDGES) {
        int d = ei[N_EDGES + e];   // dst row
        atomicAdd(&count[d], 1);
    }
}

__global__ void k_reduce(const int* __restrict__ count, int* __restrict__ bsum) {
    __shared__ int s[256];
    int t = threadIdx.x;
    int i = blockIdx.x * 256 + t;
    s[t] = (i < N_NODES) ? count[i] : 0;
    __syncthreads();
    for (int d = 128; d > 0; d >>= 1) {
        if (t < d) s[t] += s[t + d];
        __syncthreads();
    }
    if (t == 0) bsum[blockIdx.x] = s[0];
}

__global__ void k_scan_bsum(int* __restrict__ bsum, int nb) {
    if (threadIdx.x == 0 && blockIdx.x == 0) {
        int run = 0;
        for (int b = 0; b < nb; ++b) {
            int v = bsum[b];
            bsum[b] = run;
            run += v;
        }
    }
}

__global__ void k_offsets(const int* __restrict__ count, const int* __restrict__ boff,
                          int* __restrict__ offsets, float* __restrict__ dinv) {
    __shared__ int s[256];
    int t = threadIdx.x;
    int i = blockIdx.x * 256 + t;
    int c = (i < N_NODES) ? count[i] : 0;
    s[t] = c;
    __syncthreads();
    int v = c;
    for (int d = 1; d < 256; d <<= 1) {
        int w = 0;
        if (t >= d) w = s[t - d];
        __syncthreads();
        v += w;
        s[t] = v;
        __syncthreads();
    }
    int excl = v - c;
    if (i < N_NODES) {
        offsets[i] = boff[blockIdx.x] + excl;
        dinv[i] = rsqrtf((float)c + 1.0f);   // +1 self-loop, always > 0
    }
    if (blockIdx.x == 0 && t == 0) offsets[N_NODES] = N_EDGES;
}

__global__ void k_fill(const int* __restrict__ ei, const int* __restrict__ offsets,
                       int* __restrict__ cursor, int* __restrict__ csr_src) {
    int e = blockIdx.x * 256 + threadIdx.x;
    if (e < N_EDGES) {
        int s = ei[e];
        int d = ei[N_EDGES + e];
        int p = atomicAdd(&cursor[d], 1);
        csr_src[offsets[d] + p] = s;
    }
}

// ---------------------------------------------------------------------------
// f32 GEMM: C[M][128] = A[M][128] @ W[128][128], optional relu on A-load.
// Block = 256 threads, 32 rows/block. W (64KB) + Xtile (16KB) in LDS.
// Per thread: 4 rows x 4 cols (float4 acc[4]).
// ---------------------------------------------------------------------------
template <bool RELU>
__global__ __launch_bounds__(256, 2) void k_gemm(const float* __restrict__ A,
                                                 const float* __restrict__ W,
                                                 float* __restrict__ Cout) {
    __shared__ float Ws[128 * 128];
    __shared__ float Xs[32 * 128];
    int tid = threadIdx.x;
    int row0 = blockIdx.x * 32;

    const float4* W4 = (const float4*)W;
    float4* Ws4 = (float4*)Ws;
#pragma unroll
    for (int i = 0; i < 16; ++i) Ws4[tid + 256 * i] = W4[tid + 256 * i];

    float4* Xs4 = (float4*)Xs;
    const float4* A4 = (const float4*)A;
#pragma unroll
    for (int i = 0; i < 4; ++i) {
        int idx = tid + 256 * i;
        int r = idx >> 5, c4 = idx & 31;
        int gr = row0 + r;
        float4 v = make_float4(0.f, 0.f, 0.f, 0.f);
        if (gr < N_NODES) v = A4[gr * 32 + c4];
        if (RELU) {
            v.x = fmaxf(v.x, 0.f); v.y = fmaxf(v.y, 0.f);
            v.z = fmaxf(v.z, 0.f); v.w = fmaxf(v.w, 0.f);
        }
        Xs4[idx] = v;
    }
    __syncthreads();

    int cg = tid & 31;   // cols cg*4 .. cg*4+3
    int rg = tid >> 5;   // rows rg*4 .. rg*4+3
    float4 acc[4];
#pragma unroll
    for (int i = 0; i < 4; ++i) acc[i] = make_float4(0.f, 0.f, 0.f, 0.f);

    for (int k0 = 0; k0 < 128; k0 += 4) {
        float4 w0 = Ws4[(k0 + 0) * 32 + cg];
        float4 w1 = Ws4[(k0 + 1) * 32 + cg];
        float4 w2 = Ws4[(k0 + 2) * 32 + cg];
        float4 w3 = Ws4[(k0 + 3) * 32 + cg];
#pragma unroll
        for (int i = 0; i < 4; ++i) {
            float4 xi = Xs4[(rg * 4 + i) * 32 + (k0 >> 2)];
            acc[i].x += xi.x * w0.x + xi.y * w1.x + xi.z * w2.x + xi.w * w3.x;
            acc[i].y += xi.x * w0.y + xi.y * w1.y + xi.z * w2.y + xi.w * w3.y;
            acc[i].z += xi.x * w0.z + xi.y * w1.z + xi.z * w2.z + xi.w * w3.z;
            acc[i].w += xi.x * w0.w + xi.y * w1.w + xi.z * w2.w + xi.w * w3.w;
        }
    }

    float4* C4 = (float4*)Cout;
#pragma unroll
    for (int i = 0; i < 4; ++i) {
        int gr = row0 + rg * 4 + i;
        if (gr < N_NODES) C4[gr * 32 + cg] = acc[i];
    }
}

// ---------------------------------------------------------------------------
// Pull aggregation: agg[n] = dinv[n]*sum_{s in in(n)} dinv[s]*h[s]
//                            + dinv[n]^2*h[n] + bias     (pre-relu)
// One wave (64 lanes) per node; lane handles 2 channels (float2).
// ---------------------------------------------------------------------------
__global__ __launch_bounds__(256) void k_agg(const float* __restrict__ h,
                                             const int* __restrict__ offsets,
                                             const int* __restrict__ csr_src,
                                             const float* __restrict__ dinv,
                                             const float* __restrict__ bias,
                                             float* __restrict__ agg) {
    int wave = (blockIdx.x * 256 + threadIdx.x) >> 6;
    int lane = threadIdx.x & 63;
    if (wave >= N_NODES) return;
    int n = wave;
    int o0 = offsets[n], o1 = offsets[n + 1];
    float dv = dinv[n];
    const float2* h2 = (const float2*)h;
    float2 acc = make_float2(0.f, 0.f);

    int e = o0;
    for (; e + 4 <= o1; e += 4) {
        int s0 = csr_src[e], s1 = csr_src[e + 1], s2 = csr_src[e + 2], s3 = csr_src[e + 3];
        float d0 = dinv[s0], d1 = dinv[s1], d2 = dinv[s2], d3 = dinv[s3];
        float2 v0 = h2[s0 * 64 + lane];
        float2 v1 = h2[s1 * 64 + lane];
        float2 v2 = h2[s2 * 64 + lane];
        float2 v3 = h2[s3 * 64 + lane];
        acc.x += d0 * v0.x + d1 * v1.x + d2 * v2.x + d3 * v3.x;
        acc.y += d0 * v0.y + d1 * v1.y + d2 * v2.y + d3 * v3.y;
    }
    for (; e < o1; ++e) {
        int s = csr_src[e];
        float ds = dinv[s];
        float2 v = h2[s * 64 + lane];
        acc.x += ds * v.x;
        acc.y += ds * v.y;
    }

    float2 hv = h2[n * 64 + lane];
    float2 bv = ((const float2*)bias)[lane];
    float2 o;
    o.x = dv * acc.x + dv * dv * hv.x + bv.x;
    o.y = dv * acc.y + dv * dv * hv.y + bv.y;
    ((float2*)agg)[n * 64 + lane] = o;
}

// ---------------------------------------------------------------------------
// Final: out[n] = sum_c relu(agg[n][c]) * Wlin[c] + blin. One wave per node.
// ---------------------------------------------------------------------------
__global__ __launch_bounds__(256) void k_final(const float* __restrict__ agg,
                                               const float* __restrict__ Wlin,
                                               const float* __restrict__ blin,
                                               float* __restrict__ out) {
    int wave = (blockIdx.x * 256 + threadIdx.x) >> 6;
    int lane = threadIdx.x & 63;
    if (wave >= N_NODES) return;
    int n = wave;
    float a0 = fmaxf(agg[n * 128 + lane], 0.f);
    float a1 = fmaxf(agg[n * 128 + 64 + lane], 0.f);
    float v = a0 * Wlin[lane] + a1 * Wlin[64 + lane];
#pragma unroll
    for (int d = 32; d > 0; d >>= 1) v += __shfl_down(v, d, 64);
    if (lane == 0) out[n] = v + blin[0];
}

// ---------------------------------------------------------------------------
extern "C" void kernel_launch(void* const* d_in, const int* in_sizes, int n_in,
                              void* d_out, int out_size, void* d_ws, size_t ws_size,
                              hipStream_t stream) {
    const float* x    = (const float*)d_in[0];
    const int*   ei   = (const int*)d_in[2];     // [2][E] int32
    const float* W1   = (const float*)d_in[4];
    const float* b1   = (const float*)d_in[5];
    const float* W2   = (const float*)d_in[6];
    const float* b2   = (const float*)d_in[7];
    const float* Wlin = (const float*)d_in[8];
    const float* blin = (const float*)d_in[9];
    float* out = (float*)d_out;

    char* ws = (char*)d_ws;
    size_t off = 0;
    auto carve = [&](size_t bytes) -> void* {
        void* p = ws + off;
        off = (off + bytes + 255) & ~(size_t)255;
        return p;
    };
    int*   count   = (int*)  carve(N_NODES * sizeof(int));
    int*   cursor  = (int*)  carve(N_NODES * sizeof(int));
    int*   offsets = (int*)  carve((N_NODES + 1) * sizeof(int));
    float* dinv    = (float*)carve(N_NODES * sizeof(float));
    int*   bsum    = (int*)  carve(256 * sizeof(int));
    int*   csr_src = (int*)  carve(N_EDGES * sizeof(int));
    float* h       = (float*)carve((size_t)N_NODES * C * sizeof(float));
    float* agg     = (float*)carve((size_t)N_NODES * C * sizeof(float));

    const int NB_E = (N_EDGES + 255) / 256;   // 3125
    const int NB_N = (N_NODES + 255) / 256;   // 196
    const int NB_G = (N_NODES + 31) / 32;     // 1563 gemm blocks
    const int NB_W = (N_NODES + 3) / 4;       // 12500 wave-per-node blocks

    hipMemsetAsync(count, 0, N_NODES * sizeof(int), stream);
    hipMemsetAsync(cursor, 0, N_NODES * sizeof(int), stream);

    // CSR build (shared by both layers)
    k_count<<<NB_E, 256, 0, stream>>>(ei, count);
    k_reduce<<<NB_N, 256, 0, stream>>>(count, bsum);
    k_scan_bsum<<<1, 64, 0, stream>>>(bsum, NB_N);
    k_offsets<<<NB_N, 256, 0, stream>>>(count, bsum, offsets, dinv);
    k_fill<<<NB_E, 256, 0, stream>>>(ei, offsets, cursor, csr_src);

    // Layer 1
    k_gemm<false><<<NB_G, 256, 0, stream>>>(x, W1, h);
    k_agg<<<NB_W, 256, 0, stream>>>(h, offsets, csr_src, dinv, b1, agg);

    // Layer 2 (relu fused into GEMM A-load)
    k_gemm<true><<<NB_G, 256, 0, stream>>>(agg, W2, h);
    k_agg<<<NB_W, 256, 0, stream>>>(h, offsets, csr_src, dinv, b2, agg);

    // Final linear (relu fused)
    k_final<<<NB_W, 256, 0, stream>>>(agg, Wlin, blin, out);
}

// Round 2
// 370.420 us; speedup vs baseline: 1.0212x; 1.0212x over previous
//
#include <hip/hip_runtime.h>
#include <hip/hip_bf16.h>

#define N_NODES 50000
#define N_EDGES 800000
#define C 128

// ---------------------------------------------------------------------------
// CSR build: count in-degrees, prefix-sum to offsets, fill src lists.
// ---------------------------------------------------------------------------
__global__ void k_count(const int* __restrict__ ei, int* __restrict__ count) {
    int e = blockIdx.x * 256 + threadIdx.x;
    if (e < N_EDGES) {
        int d = ei[N_EDGES + e];   // dst row
        atomicAdd(&count[d], 1);
    }
}

__global__ void k_reduce(const int* __restrict__ count, int* __restrict__ bsum) {
    __shared__ int s[256];
    int t = threadIdx.x;
    int i = blockIdx.x * 256 + t;
    s[t] = (i < N_NODES) ? count[i] : 0;
    __syncthreads();
    for (int d = 128; d > 0; d >>= 1) {
        if (t < d) s[t] += s[t + d];
        __syncthreads();
    }
    if (t == 0) bsum[blockIdx.x] = s[0];
}

// Parallel exclusive scan over nb (<=256) block sums: one 256-thread block.
__global__ void k_scan_bsum(int* __restrict__ bsum, int nb) {
    __shared__ int ws[4];
    int t = threadIdx.x;
    int lane = t & 63, w = t >> 6;
    int v = (t < nb) ? bsum[t] : 0;
    int s = v;
#pragma unroll
    for (int d = 1; d < 64; d <<= 1) {
        int u = __shfl_up(s, d, 64);
        if (lane >= d) s += u;
    }
    if (lane == 63) ws[w] = s;
    __syncthreads();
    int add = 0;
    for (int i = 0; i < w; ++i) add += ws[i];
    int excl = s + add - v;
    if (t < nb) bsum[t] = excl;
}

__global__ void k_offsets(const int* __restrict__ count, const int* __restrict__ boff,
                          int* __restrict__ offsets, float* __restrict__ dinv) {
    __shared__ int s[256];
    int t = threadIdx.x;
    int i = blockIdx.x * 256 + t;
    int c = (i < N_NODES) ? count[i] : 0;
    s[t] = c;
    __syncthreads();
    int v = c;
    for (int d = 1; d < 256; d <<= 1) {
        int w = 0;
        if (t >= d) w = s[t - d];
        __syncthreads();
        v += w;
        s[t] = v;
        __syncthreads();
    }
    int excl = v - c;
    if (i < N_NODES) {
        offsets[i] = boff[blockIdx.x] + excl;
        dinv[i] = rsqrtf((float)c + 1.0f);   // +1 self-loop, always > 0
    }
    if (blockIdx.x == 0 && t == 0) offsets[N_NODES] = N_EDGES;
}

__global__ void k_fill(const int* __restrict__ ei, const int* __restrict__ offsets,
                       int* __restrict__ cursor, int* __restrict__ csr_src) {
    int e = blockIdx.x * 256 + threadIdx.x;
    if (e < N_EDGES) {
        int s = ei[e];
        int d = ei[N_EDGES + e];
        int p = atomicAdd(&cursor[d], 1);
        csr_src[offsets[d] + p] = s;
    }
}

// ---------------------------------------------------------------------------
// f32 GEMM: C[M][128] = A[M][128] @ W[128][128], optional relu on A-load.
// Block = 256 threads, 128 rows x 128 cols per block, 8x8 per thread.
// Ws 64KB + Xs (padded stride 132 floats) 66KB = 130KB LDS -> 1 block/CU.
// reads/FMA = 1/32 + 1/32 (vs 1/16+1/16 for 4x4) -> LDS-bound time halves.
// ---------------------------------------------------------------------------
#define XS_STRIDE 132   // 128 + 4 floats pad; 528 B, 16B-aligned

template <bool RELU>
__global__ __launch_bounds__(256, 1) void k_gemm(const float* __restrict__ A,
                                                 const float* __restrict__ W,
                                                 float* __restrict__ Cout) {
    __shared__ float Ws[128 * 128];        // k-major: Ws4[k*32 + c4]
    __shared__ float Xs[128 * XS_STRIDE];  // row-major, padded
    int tid = threadIdx.x;
    int row0 = blockIdx.x * 128;

    const float4* W4 = (const float4*)W;
    float4* Ws4 = (float4*)Ws;
#pragma unroll
    for (int i = 0; i < 16; ++i) Ws4[tid + 256 * i] = W4[tid + 256 * i];

    const float4* A4 = (const float4*)A;
#pragma unroll
    for (int i = 0; i < 16; ++i) {
        int idx = tid + 256 * i;          // 0..4095
        int r = idx >> 5, c4 = idx & 31;
        int gr = row0 + r;
        float4 v = make_float4(0.f, 0.f, 0.f, 0.f);
        if (gr < N_NODES) v = A4[gr * 32 + c4];
        if (RELU) {
            v.x = fmaxf(v.x, 0.f); v.y = fmaxf(v.y, 0.f);
            v.z = fmaxf(v.z, 0.f); v.w = fmaxf(v.w, 0.f);
        }
        *(float4*)(Xs + r * XS_STRIDE + c4 * 4) = v;
    }
    __syncthreads();

    int cg = tid & 15;   // cols cg*8 .. cg*8+7 (two float4s)
    int rg = tid >> 4;   // rows rg*8 .. rg*8+7
    float4 acc[8][2];
#pragma unroll
    for (int i = 0; i < 8; ++i) {
        acc[i][0] = make_float4(0.f, 0.f, 0.f, 0.f);
        acc[i][1] = make_float4(0.f, 0.f, 0.f, 0.f);
    }

    for (int k0 = 0; k0 < 128; k0 += 4) {
        float4 wv[4][2];
#pragma unroll
        for (int kk = 0; kk < 4; ++kk) {
            wv[kk][0] = Ws4[(k0 + kk) * 32 + cg * 2];
            wv[kk][1] = Ws4[(k0 + kk) * 32 + cg * 2 + 1];
        }
        float4 xv[8];
#pragma unroll
        for (int i = 0; i < 8; ++i)
            xv[i] = *(const float4*)(Xs + (rg * 8 + i) * XS_STRIDE + k0);
#pragma unroll
        for (int i = 0; i < 8; ++i) {
#pragma unroll
            for (int kk = 0; kk < 4; ++kk) {
                float xs = (kk == 0) ? xv[i].x : (kk == 1) ? xv[i].y
                         : (kk == 2) ? xv[i].z : xv[i].w;
                acc[i][0].x += xs * wv[kk][0].x;
                acc[i][0].y += xs * wv[kk][0].y;
                acc[i][0].z += xs * wv[kk][0].z;
                acc[i][0].w += xs * wv[kk][0].w;
                acc[i][1].x += xs * wv[kk][1].x;
                acc[i][1].y += xs * wv[kk][1].y;
                acc[i][1].z += xs * wv[kk][1].z;
                acc[i][1].w += xs * wv[kk][1].w;
            }
        }
    }

    float4* C4 = (float4*)Cout;
#pragma unroll
    for (int i = 0; i < 8; ++i) {
        int gr = row0 + rg * 8 + i;
        if (gr < N_NODES) {
            C4[gr * 32 + cg * 2]     = acc[i][0];
            C4[gr * 32 + cg * 2 + 1] = acc[i][1];
        }
    }
}

// ---------------------------------------------------------------------------
// Pull aggregation: pre-relu agg[n] = dinv[n]*sum_s dinv[s]*h[s] + dinv[n]^2*h[n] + b
// One wave per node; lane handles 2 channels (float2). 8-deep unrolled gather
// for MLP. FINAL variant fuses relu + 128->1 linear + wave reduce -> out[n].
// ---------------------------------------------------------------------------
template <bool FINAL>
__global__ __launch_bounds__(256) void k_agg(const float* __restrict__ h,
                                             const int* __restrict__ offsets,
                                             const int* __restrict__ csr_src,
                                             const float* __restrict__ dinv,
                                             const float* __restrict__ bias,
                                             const float* __restrict__ Wlin,
                                             const float* __restrict__ blin,
                                             float* __restrict__ aggout) {
    int wave = (blockIdx.x * 256 + threadIdx.x) >> 6;
    int lane = threadIdx.x & 63;
    if (wave >= N_NODES) return;
    int n = wave;
    int o0 = offsets[n], o1 = offsets[n + 1];
    float dv = dinv[n];
    const float2* h2 = (const float2*)h;
    float2 acc = make_float2(0.f, 0.f);

    int e = o0;
    for (; e + 8 <= o1; e += 8) {
        int s[8];
#pragma unroll
        for (int j = 0; j < 8; ++j) s[j] = csr_src[e + j];
        float d[8];
#pragma unroll
        for (int j = 0; j < 8; ++j) d[j] = dinv[s[j]];
        float2 v[8];
#pragma unroll
        for (int j = 0; j < 8; ++j) v[j] = h2[s[j] * 64 + lane];
#pragma unroll
        for (int j = 0; j < 8; ++j) {
            acc.x += d[j] * v[j].x;
            acc.y += d[j] * v[j].y;
        }
    }
    for (; e < o1; ++e) {
        int s = csr_src[e];
        float ds = dinv[s];
        float2 v = h2[s * 64 + lane];
        acc.x += ds * v.x;
        acc.y += ds * v.y;
    }

    float2 hv = h2[n * 64 + lane];
    float2 bv = ((const float2*)bias)[lane];
    float2 o;
    o.x = dv * acc.x + dv * dv * hv.x + bv.x;
    o.y = dv * acc.y + dv * dv * hv.y + bv.y;

    if (!FINAL) {
        ((float2*)aggout)[n * 64 + lane] = o;
    } else {
        float2 wl = ((const float2*)Wlin)[lane];
        float v = fmaxf(o.x, 0.f) * wl.x + fmaxf(o.y, 0.f) * wl.y;
#pragma unroll
        for (int d = 32; d > 0; d >>= 1) v += __shfl_down(v, d, 64);
        if (lane == 0) aggout[n] = v + blin[0];
    }
}

// ---------------------------------------------------------------------------
extern "C" void kernel_launch(void* const* d_in, const int* in_sizes, int n_in,
                              void* d_out, int out_size, void* d_ws, size_t ws_size,
                              hipStream_t stream) {
    const float* x    = (const float*)d_in[0];
    const int*   ei   = (const int*)d_in[2];     // [2][E] int32
    const float* W1   = (const float*)d_in[4];
    const float* b1   = (const float*)d_in[5];
    const float* W2   = (const float*)d_in[6];
    const float* b2   = (const float*)d_in[7];
    const float* Wlin = (const float*)d_in[8];
    const float* blin = (const float*)d_in[9];
    float* out = (float*)d_out;

    char* ws = (char*)d_ws;
    size_t off = 0;
    auto carve = [&](size_t bytes) -> void* {
        void* p = ws + off;
        off = (off + bytes + 255) & ~(size_t)255;
        return p;
    };
    int*   count   = (int*)  carve(2 * N_NODES * sizeof(int));  // count + cursor adjacent
    int*   cursor  = count + N_NODES;
    int*   offsets = (int*)  carve((N_NODES + 1) * sizeof(int));
    float* dinv    = (float*)carve(N_NODES * sizeof(float));
    int*   bsum    = (int*)  carve(256 * sizeof(int));
    int*   csr_src = (int*)  carve(N_EDGES * sizeof(int));
    float* h       = (float*)carve((size_t)N_NODES * C * sizeof(float));
    float* agg     = (float*)carve((size_t)N_NODES * C * sizeof(float));

    const int NB_E = (N_EDGES + 255) / 256;    // 3125
    const int NB_N = (N_NODES + 255) / 256;    // 196
    const int NB_G = (N_NODES + 127) / 128;    // 391 gemm blocks
    const int NB_W = (N_NODES + 3) / 4;        // 12500 wave-per-node blocks

    hipMemsetAsync(count, 0, 2 * N_NODES * sizeof(int), stream);  // count + cursor

    // CSR build (shared by both layers)
    k_count<<<NB_E, 256, 0, stream>>>(ei, count);
    k_reduce<<<NB_N, 256, 0, stream>>>(count, bsum);
    k_scan_bsum<<<1, 256, 0, stream>>>(bsum, NB_N);
    k_offsets<<<NB_N, 256, 0, stream>>>(count, bsum, offsets, dinv);
    k_fill<<<NB_E, 256, 0, stream>>>(ei, offsets, cursor, csr_src);

    // Layer 1
    k_gemm<false><<<NB_G, 256, 0, stream>>>(x, W1, h);
    k_agg<false><<<NB_W, 256, 0, stream>>>(h, offsets, csr_src, dinv, b1, Wlin, blin, agg);

    // Layer 2 (relu fused into GEMM A-load)
    k_gemm<true><<<NB_G, 256, 0, stream>>>(agg, W2, h);

    // Layer-2 aggregation with fused relu + final linear -> out
    k_agg<true><<<NB_W, 256, 0, stream>>>(h, offsets, csr_src, dinv, b2, Wlin, blin, out);
}

// Round 3
// 316.663 us; speedup vs baseline: 1.1946x; 1.1698x over previous
//
#include <hip/hip_runtime.h>
#include <hip/hip_bf16.h>

#define N_NODES 50000
#define N_EDGES 800000
#define C 128

// ---------------------------------------------------------------------------
// CSR build: count in-degrees, prefix-sum to offsets, fill src lists.
// ---------------------------------------------------------------------------
__global__ void k_count(const int* __restrict__ ei, int* __restrict__ count) {
    int e = blockIdx.x * 256 + threadIdx.x;
    if (e < N_EDGES) {
        int d = ei[N_EDGES + e];   // dst row
        atomicAdd(&count[d], 1);
    }
}

__global__ void k_reduce(const int* __restrict__ count, int* __restrict__ bsum) {
    __shared__ int s[256];
    int t = threadIdx.x;
    int i = blockIdx.x * 256 + t;
    s[t] = (i < N_NODES) ? count[i] : 0;
    __syncthreads();
    for (int d = 128; d > 0; d >>= 1) {
        if (t < d) s[t] += s[t + d];
        __syncthreads();
    }
    if (t == 0) bsum[blockIdx.x] = s[0];
}

// Parallel exclusive scan over nb (<=256) block sums: one 256-thread block.
__global__ void k_scan_bsum(int* __restrict__ bsum, int nb) {
    __shared__ int ws[4];
    int t = threadIdx.x;
    int lane = t & 63, w = t >> 6;
    int v = (t < nb) ? bsum[t] : 0;
    int s = v;
#pragma unroll
    for (int d = 1; d < 64; d <<= 1) {
        int u = __shfl_up(s, d, 64);
        if (lane >= d) s += u;
    }
    if (lane == 63) ws[w] = s;
    __syncthreads();
    int add = 0;
    for (int i = 0; i < w; ++i) add += ws[i];
    int excl = s + add - v;
    if (t < nb) bsum[t] = excl;
}

__global__ void k_offsets(const int* __restrict__ count, const int* __restrict__ boff,
                          int* __restrict__ offsets, float* __restrict__ dinv) {
    __shared__ int s[256];
    int t = threadIdx.x;
    int i = blockIdx.x * 256 + t;
    int c = (i < N_NODES) ? count[i] : 0;
    s[t] = c;
    __syncthreads();
    int v = c;
    for (int d = 1; d < 256; d <<= 1) {
        int w = 0;
        if (t >= d) w = s[t - d];
        __syncthreads();
        v += w;
        s[t] = v;
        __syncthreads();
    }
    int excl = v - c;
    if (i < N_NODES) {
        offsets[i] = boff[blockIdx.x] + excl;
        dinv[i] = rsqrtf((float)c + 1.0f);   // +1 self-loop, always > 0
    }
    if (blockIdx.x == 0 && t == 0) offsets[N_NODES] = N_EDGES;
}

__global__ void k_fill(const int* __restrict__ ei, const int* __restrict__ offsets,
                       int* __restrict__ cursor, int* __restrict__ csr_src) {
    int e = blockIdx.x * 256 + threadIdx.x;
    if (e < N_EDGES) {
        int s = ei[e];
        int d = ei[N_EDGES + e];
        int p = atomicAdd(&cursor[d], 1);
        csr_src[offsets[d] + p] = s;
    }
}

// ---------------------------------------------------------------------------
// bf16 pack helpers (RTN)
// ---------------------------------------------------------------------------
__device__ __forceinline__ unsigned int bf16rtn(float f) {
    unsigned int u = __float_as_uint(f);
    return (u + 0x7fffu + ((u >> 16) & 1u)) >> 16;
}
__device__ __forceinline__ unsigned int packbf2(float lo, float hi) {
    return bf16rtn(lo) | (bf16rtn(hi) << 16);
}

// ---------------------------------------------------------------------------
// f32 GEMM -> bf16 out: H[M][128]bf16 = A[M][128]f32 @ W[128][128]f32.
// Block 256 thr, tile 64 rows x 128 cols, K-panels of 32 staged in LDS.
// LDS = Wp 16KB + Xs 64x44 pad 11.3KB = 27.3KB -> high occupancy.
// Per thread 4 rows x (two float4 col-halves 64 apart): Wp reads 2-way
// bank-aliased (free), Xs stride-44 reads conflict-free.
// ---------------------------------------------------------------------------
#define XS_STRIDE 44   // floats; 176B, 16B-aligned; banks {0,12,24,4} per rg

template <bool RELU>
__global__ __launch_bounds__(256, 2) void k_gemm(const float* __restrict__ A,
                                                 const float* __restrict__ W,
                                                 unsigned int* __restrict__ Hout) {
    __shared__ float Wp[32 * 128];          // k-major panel: Wp4[kk*32 + j4]
    __shared__ float Xs[64 * XS_STRIDE];    // row-major, padded
    int tid = threadIdx.x;
    int cg = tid & 15;    // col group: cols cg*4..+3 and 64+cg*4..+3
    int rg = tid >> 4;    // row group: rows rg*4..+3
    int row0 = blockIdx.x * 64;

    const float4* W4 = (const float4*)W;
    const float4* A4 = (const float4*)A;
    float4* Wp4 = (float4*)Wp;

    float4 acc[4][2];
#pragma unroll
    for (int i = 0; i < 4; ++i) {
        acc[i][0] = make_float4(0.f, 0.f, 0.f, 0.f);
        acc[i][1] = make_float4(0.f, 0.f, 0.f, 0.f);
    }

    for (int p = 0; p < 4; ++p) {
        if (p) __syncthreads();   // previous panel fully consumed
#pragma unroll
        for (int i = 0; i < 4; ++i)
            Wp4[tid + 256 * i] = W4[p * 1024 + tid + 256 * i];
#pragma unroll
        for (int i = 0; i < 2; ++i) {
            int idx = tid + 256 * i;      // 0..511
            int r = idx >> 3, c4 = idx & 7;
            int gr = row0 + r;
            float4 v = make_float4(0.f, 0.f, 0.f, 0.f);
            if (gr < N_NODES) v = A4[gr * 32 + p * 8 + c4];
            if (RELU) {
                v.x = fmaxf(v.x, 0.f); v.y = fmaxf(v.y, 0.f);
                v.z = fmaxf(v.z, 0.f); v.w = fmaxf(v.w, 0.f);
            }
            *(float4*)(Xs + r * XS_STRIDE + c4 * 4) = v;
        }
        __syncthreads();

#pragma unroll
        for (int k0 = 0; k0 < 32; k0 += 4) {
            float4 wv[4][2];
#pragma unroll
            for (int kk = 0; kk < 4; ++kk) {
                wv[kk][0] = Wp4[(k0 + kk) * 32 + cg];
                wv[kk][1] = Wp4[(k0 + kk) * 32 + 16 + cg];
            }
            float4 xv[4];
#pragma unroll
            for (int i = 0; i < 4; ++i)
                xv[i] = *(const float4*)(Xs + (rg * 4 + i) * XS_STRIDE + k0);
#pragma unroll
            for (int i = 0; i < 4; ++i) {
#pragma unroll
                for (int kk = 0; kk < 4; ++kk) {
                    float xs = (kk == 0) ? xv[i].x : (kk == 1) ? xv[i].y
                             : (kk == 2) ? xv[i].z : xv[i].w;
#pragma unroll
                    for (int h = 0; h < 2; ++h) {
                        acc[i][h].x += xs * wv[kk][h].x;
                        acc[i][h].y += xs * wv[kk][h].y;
                        acc[i][h].z += xs * wv[kk][h].z;
                        acc[i][h].w += xs * wv[kk][h].w;
                    }
                }
            }
        }
    }

    // Epilogue: pack to bf16 (row = 64 uints of 2 bf16 each)
#pragma unroll
    for (int i = 0; i < 4; ++i) {
        int gr = row0 + rg * 4 + i;
        if (gr < N_NODES) {
            uint2 u0, u1;
            u0.x = packbf2(acc[i][0].x, acc[i][0].y);
            u0.y = packbf2(acc[i][0].z, acc[i][0].w);
            u1.x = packbf2(acc[i][1].x, acc[i][1].y);
            u1.y = packbf2(acc[i][1].z, acc[i][1].w);
            *(uint2*)&Hout[gr * 64 + cg * 2]      = u0;   // cols cg*4..+3
            *(uint2*)&Hout[gr * 64 + 32 + cg * 2] = u1;   // cols 64+cg*4..+3
        }
    }
}

// ---------------------------------------------------------------------------
// Pull aggregation over bf16 H: pre-relu
//   agg[n] = dinv[n]*sum_s dinv[s]*H[s] + dinv[n]^2*H[n] + b
// One wave per node; lane holds 2 channels (one packed uint). FINAL fuses
// relu + 128->1 linear + wave reduce -> out[n].
// ---------------------------------------------------------------------------
template <bool FINAL>
__global__ __launch_bounds__(256) void k_agg(const unsigned int* __restrict__ h,
                                             const int* __restrict__ offsets,
                                             const int* __restrict__ csr_src,
                                             const float* __restrict__ dinv,
                                             const float* __restrict__ bias,
                                             const float* __restrict__ Wlin,
                                             const float* __restrict__ blin,
                                             float* __restrict__ aggout) {
    int wave = (blockIdx.x * 256 + threadIdx.x) >> 6;
    int lane = threadIdx.x & 63;
    if (wave >= N_NODES) return;
    int n = wave;
    int o0 = offsets[n], o1 = offsets[n + 1];
    float dv = dinv[n];
    float ax = 0.f, ay = 0.f;

    int e = o0;
    for (; e + 8 <= o1; e += 8) {
        int s[8];
#pragma unroll
        for (int j = 0; j < 8; ++j) s[j] = csr_src[e + j];
        float d[8];
#pragma unroll
        for (int j = 0; j < 8; ++j) d[j] = dinv[s[j]];
        unsigned int u[8];
#pragma unroll
        for (int j = 0; j < 8; ++j) u[j] = h[s[j] * 64 + lane];
#pragma unroll
        for (int j = 0; j < 8; ++j) {
            ax += d[j] * __uint_as_float(u[j] << 16);
            ay += d[j] * __uint_as_float(u[j] & 0xffff0000u);
        }
    }
    for (; e < o1; ++e) {
        int s = csr_src[e];
        float ds = dinv[s];
        unsigned int u = h[s * 64 + lane];
        ax += ds * __uint_as_float(u << 16);
        ay += ds * __uint_as_float(u & 0xffff0000u);
    }

    unsigned int us = h[n * 64 + lane];
    float hx = __uint_as_float(us << 16);
    float hy = __uint_as_float(us & 0xffff0000u);
    float2 bv = ((const float2*)bias)[lane];
    float ox = dv * ax + dv * dv * hx + bv.x;
    float oy = dv * ay + dv * dv * hy + bv.y;

    if (!FINAL) {
        ((float2*)aggout)[n * 64 + lane] = make_float2(ox, oy);
    } else {
        float2 wl = ((const float2*)Wlin)[lane];
        float v = fmaxf(ox, 0.f) * wl.x + fmaxf(oy, 0.f) * wl.y;
#pragma unroll
        for (int d = 32; d > 0; d >>= 1) v += __shfl_down(v, d, 64);
        if (lane == 0) aggout[n] = v + blin[0];
    }
}

// ---------------------------------------------------------------------------
extern "C" void kernel_launch(void* const* d_in, const int* in_sizes, int n_in,
                              void* d_out, int out_size, void* d_ws, size_t ws_size,
                              hipStream_t stream) {
    const float* x    = (const float*)d_in[0];
    const int*   ei   = (const int*)d_in[2];     // [2][E] int32
    const float* W1   = (const float*)d_in[4];
    const float* b1   = (const float*)d_in[5];
    const float* W2   = (const float*)d_in[6];
    const float* b2   = (const float*)d_in[7];
    const float* Wlin = (const float*)d_in[8];
    const float* blin = (const float*)d_in[9];
    float* out = (float*)d_out;

    char* ws = (char*)d_ws;
    size_t off = 0;
    auto carve = [&](size_t bytes) -> void* {
        void* p = ws + off;
        off = (off + bytes + 255) & ~(size_t)255;
        return p;
    };
    int*   count   = (int*)  carve(2 * N_NODES * sizeof(int));  // count + cursor adjacent
    int*   cursor  = count + N_NODES;
    int*   offsets = (int*)  carve((N_NODES + 1) * sizeof(int));
    float* dinv    = (float*)carve(N_NODES * sizeof(float));
    int*   bsum    = (int*)  carve(256 * sizeof(int));
    int*   csr_src = (int*)  carve(N_EDGES * sizeof(int));
    unsigned int* hbf = (unsigned int*)carve((size_t)N_NODES * 64 * sizeof(unsigned int)); // bf16 H
    float* agg     = (float*)carve((size_t)N_NODES * C * sizeof(float));

    const int NB_E = (N_EDGES + 255) / 256;    // 3125
    const int NB_N = (N_NODES + 255) / 256;    // 196
    const int NB_G = (N_NODES + 63) / 64;      // 782 gemm blocks
    const int NB_W = (N_NODES + 3) / 4;        // 12500 wave-per-node blocks

    hipMemsetAsync(count, 0, 2 * N_NODES * sizeof(int), stream);  // count + cursor

    // CSR build (shared by both layers)
    k_count<<<NB_E, 256, 0, stream>>>(ei, count);
    k_reduce<<<NB_N, 256, 0, stream>>>(count, bsum);
    k_scan_bsum<<<1, 256, 0, stream>>>(bsum, NB_N);
    k_offsets<<<NB_N, 256, 0, stream>>>(count, bsum, offsets, dinv);
    k_fill<<<NB_E, 256, 0, stream>>>(ei, offsets, cursor, csr_src);

    // Layer 1
    k_gemm<false><<<NB_G, 256, 0, stream>>>(x, W1, hbf);
    k_agg<false><<<NB_W, 256, 0, stream>>>(hbf, offsets, csr_src, dinv, b1, Wlin, blin, agg);

    // Layer 2 (relu fused into GEMM A-load, reads f32 agg)
    k_gemm<true><<<NB_G, 256, 0, stream>>>(agg, W2, hbf);

    // Layer-2 aggregation with fused relu + final linear -> out
    k_agg<true><<<NB_W, 256, 0, stream>>>(hbf, offsets, csr_src, dinv, b2, Wlin, blin, out);
}

// Round 4
// 251.006 us; speedup vs baseline: 1.5070x; 1.2616x over previous
//
#include <hip/hip_runtime.h>
#include <hip/hip_bf16.h>

#define N_NODES 50000
#define N_EDGES 800000
#define C 128

#define NBA   196      // A-buckets: dst>>8, 256 nodes each
#define CAPA  4800     // per-bucket capacity (mean 4082, +11 sigma)
#define CHUNK 2048     // edges per binA block

// ---------------------------------------------------------------------------
// k_binA: 2-level radix partition, level 1. Each block takes CHUNK edges,
// histograms by bucket (dst>>8) in LDS, scatters locally in LDS, reserves a
// per-bucket run with ONE global atomic per bucket, writes runs coalesced.
// ---------------------------------------------------------------------------
__global__ __launch_bounds__(256) void k_binA(const int* __restrict__ ei,
                                              int* __restrict__ gcur,
                                              int2* __restrict__ tmp) {
    __shared__ int hist[NBA];
    __shared__ int lbase[NBA];
    __shared__ int gbaseL[NBA];
    __shared__ int stmp[256];
    __shared__ int2 buf[CHUNK];
    __shared__ int totalv;

    int tid = threadIdx.x;
    int e0 = blockIdx.x * CHUNK;

    for (int i = tid; i < NBA; i += 256) hist[i] = 0;
    __syncthreads();

    int sarr[8], darr[8], parr[8];
#pragma unroll
    for (int j = 0; j < 8; ++j) {
        int e = e0 + j * 256 + tid;
        darr[j] = -1;
        if (e < N_EDGES) {
            sarr[j] = ei[e];
            int d = ei[N_EDGES + e];
            darr[j] = d;
            parr[j] = atomicAdd(&hist[d >> 8], 1);
        }
    }
    __syncthreads();

    // exclusive scan of hist -> lbase; total -> totalv
    {
        int c = (tid < NBA) ? hist[tid] : 0;
        stmp[tid] = c;
        __syncthreads();
        int v = c;
        for (int d = 1; d < 256; d <<= 1) {
            int w = (tid >= d) ? stmp[tid - d] : 0;
            __syncthreads();
            v += w;
            stmp[tid] = v;
            __syncthreads();
        }
        if (tid < NBA) lbase[tid] = v - c;
        if (tid == 255) totalv = v;
    }
    // reserve global runs (one atomic per bucket per block)
    if (tid < NBA) {
        int cnt = hist[tid];
        int run = (cnt > 0) ? atomicAdd(&gcur[tid], cnt) : 0;
        gbaseL[tid] = tid * CAPA + run;
    }
    __syncthreads();

    // LDS scatter
#pragma unroll
    for (int j = 0; j < 8; ++j) {
        if (darr[j] >= 0) {
            int b = darr[j] >> 8;
            buf[lbase[b] + parr[j]] = make_int2(sarr[j], darr[j]);
        }
    }
    __syncthreads();

    // coalesced write-out of per-bucket runs
    int total = totalv;
    for (int i = tid; i < total; i += 256) {
        int2 v = buf[i];
        int b = v.y >> 8;
        int idx = i - lbase[b];
        int gpos = gbaseL[b] + idx;
        if (gpos < (b + 1) * CAPA) tmp[gpos] = v;   // safety guard
    }
}

// ---------------------------------------------------------------------------
// k_scanA: exclusive scan over 196 bucket totals -> gbase; offsets[N]=E.
// ---------------------------------------------------------------------------
__global__ void k_scanA(const int* __restrict__ gcur, int* __restrict__ gbase,
                        int* __restrict__ offsets) {
    __shared__ int ws[4];
    int t = threadIdx.x;
    int lane = t & 63, w = t >> 6;
    int v = (t < NBA) ? gcur[t] : 0;
    int s = v;
#pragma unroll
    for (int d = 1; d < 64; d <<= 1) {
        int u = __shfl_up(s, d, 64);
        if (lane >= d) s += u;
    }
    if (lane == 63) ws[w] = s;
    __syncthreads();
    int add = 0;
    for (int i = 0; i < w; ++i) add += ws[i];
    if (t < NBA) gbase[t] = s + add - v;
    if (t == 0) offsets[N_NODES] = N_EDGES;
}

// ---------------------------------------------------------------------------
// k_binB: level 2. One block per bucket: stage bucket edges in LDS, count
// per-node, block-scan -> offsets/dinv, scatter csr_src into the bucket's
// contiguous (block-local) window. No global per-node atomics anywhere.
// ---------------------------------------------------------------------------
__global__ __launch_bounds__(256) void k_binB(const int2* __restrict__ tmp,
                                              const int* __restrict__ gcur,
                                              const int* __restrict__ gbase,
                                              int* __restrict__ csr_src,
                                              int* __restrict__ offsets,
                                              float* __restrict__ dinv) {
    __shared__ int2 buf[CAPA];
    __shared__ int ncnt[256];
    __shared__ int nbase[256];
    __shared__ int stmp[256];

    int b = blockIdx.x;
    int tid = threadIdx.x;
    int cnt = gcur[b];
    if (cnt > CAPA) cnt = CAPA;
    int base = gbase[b];

    ncnt[tid] = 0;
    __syncthreads();

    for (int i = tid; i < cnt; i += 256) {
        int2 v = tmp[b * CAPA + i];
        buf[i] = v;
        atomicAdd(&ncnt[v.y & 255], 1);
    }
    __syncthreads();

    // exclusive scan of ncnt -> nbase
    {
        int c = ncnt[tid];
        stmp[tid] = c;
        __syncthreads();
        int v = c;
        for (int d = 1; d < 256; d <<= 1) {
            int w = (tid >= d) ? stmp[tid - d] : 0;
            __syncthreads();
            v += w;
            stmp[tid] = v;
            __syncthreads();
        }
        nbase[tid] = v - c;
    }
    __syncthreads();

    int node = b * 256 + tid;
    if (node < N_NODES) {
        offsets[node] = base + nbase[tid];
        dinv[node] = rsqrtf((float)ncnt[tid] + 1.0f);   // +1 self-loop
    }
    __syncthreads();
    ncnt[tid] = 0;   // reuse as cursor
    __syncthreads();

    for (int i = tid; i < cnt; i += 256) {
        int2 v = buf[i];
        int l = v.y & 255;
        int p = atomicAdd(&ncnt[l], 1);
        csr_src[base + nbase[l] + p] = v.x;
    }
}

// ---------------------------------------------------------------------------
// bf16 pack helpers (RTN)
// ---------------------------------------------------------------------------
__device__ __forceinline__ unsigned int bf16rtn(float f) {
    unsigned int u = __float_as_uint(f);
    return (u + 0x7fffu + ((u >> 16) & 1u)) >> 16;
}
__device__ __forceinline__ unsigned int packbf2(float lo, float hi) {
    return bf16rtn(lo) | (bf16rtn(hi) << 16);
}

// ---------------------------------------------------------------------------
// f32 GEMM -> bf16 out (unchanged from round 3)
// ---------------------------------------------------------------------------
#define XS_STRIDE 44

template <bool RELU>
__global__ __launch_bounds__(256, 2) void k_gemm(const float* __restrict__ A,
                                                 const float* __restrict__ W,
                                                 unsigned int* __restrict__ Hout) {
    __shared__ float Wp[32 * 128];
    __shared__ float Xs[64 * XS_STRIDE];
    int tid = threadIdx.x;
    int cg = tid & 15;
    int rg = tid >> 4;
    int row0 = blockIdx.x * 64;

    const float4* W4 = (const float4*)W;
    const float4* A4 = (const float4*)A;
    float4* Wp4 = (float4*)Wp;

    float4 acc[4][2];
#pragma unroll
    for (int i = 0; i < 4; ++i) {
        acc[i][0] = make_float4(0.f, 0.f, 0.f, 0.f);
        acc[i][1] = make_float4(0.f, 0.f, 0.f, 0.f);
    }

    for (int p = 0; p < 4; ++p) {
        if (p) __syncthreads();
#pragma unroll
        for (int i = 0; i < 4; ++i)
            Wp4[tid + 256 * i] = W4[p * 1024 + tid + 256 * i];
#pragma unroll
        for (int i = 0; i < 2; ++i) {
            int idx = tid + 256 * i;
            int r = idx >> 3, c4 = idx & 7;
            int gr = row0 + r;
            float4 v = make_float4(0.f, 0.f, 0.f, 0.f);
            if (gr < N_NODES) v = A4[gr * 32 + p * 8 + c4];
            if (RELU) {
                v.x = fmaxf(v.x, 0.f); v.y = fmaxf(v.y, 0.f);
                v.z = fmaxf(v.z, 0.f); v.w = fmaxf(v.w, 0.f);
            }
            *(float4*)(Xs + r * XS_STRIDE + c4 * 4) = v;
        }
        __syncthreads();

#pragma unroll
        for (int k0 = 0; k0 < 32; k0 += 4) {
            float4 wv[4][2];
#pragma unroll
            for (int kk = 0; kk < 4; ++kk) {
                wv[kk][0] = Wp4[(k0 + kk) * 32 + cg];
                wv[kk][1] = Wp4[(k0 + kk) * 32 + 16 + cg];
            }
            float4 xv[4];
#pragma unroll
            for (int i = 0; i < 4; ++i)
                xv[i] = *(const float4*)(Xs + (rg * 4 + i) * XS_STRIDE + k0);
#pragma unroll
            for (int i = 0; i < 4; ++i) {
#pragma unroll
                for (int kk = 0; kk < 4; ++kk) {
                    float xs = (kk == 0) ? xv[i].x : (kk == 1) ? xv[i].y
                             : (kk == 2) ? xv[i].z : xv[i].w;
#pragma unroll
                    for (int h = 0; h < 2; ++h) {
                        acc[i][h].x += xs * wv[kk][h].x;
                        acc[i][h].y += xs * wv[kk][h].y;
                        acc[i][h].z += xs * wv[kk][h].z;
                        acc[i][h].w += xs * wv[kk][h].w;
                    }
                }
            }
        }
    }

#pragma unroll
    for (int i = 0; i < 4; ++i) {
        int gr = row0 + rg * 4 + i;
        if (gr < N_NODES) {
            uint2 u0, u1;
            u0.x = packbf2(acc[i][0].x, acc[i][0].y);
            u0.y = packbf2(acc[i][0].z, acc[i][0].w);
            u1.x = packbf2(acc[i][1].x, acc[i][1].y);
            u1.y = packbf2(acc[i][1].z, acc[i][1].w);
            *(uint2*)&Hout[gr * 64 + cg * 2]      = u0;
            *(uint2*)&Hout[gr * 64 + 32 + cg * 2] = u1;
        }
    }
}

// ---------------------------------------------------------------------------
// Wide pull aggregation over bf16 H. Wave per node; lane: eg=lane>>4 (edge
// subset), cq=lane&15 (channels 8cq..8cq+7 as one uint4). 8 edges/iter via
// int2 src-pairs + 2 uint4 row loads per lane (4.8x fewer load instrs).
// ---------------------------------------------------------------------------
__device__ __forceinline__ void accum8(float* acc, float d, uint4 u) {
    acc[0] += d * __uint_as_float(u.x << 16);
    acc[1] += d * __uint_as_float(u.x & 0xffff0000u);
    acc[2] += d * __uint_as_float(u.y << 16);
    acc[3] += d * __uint_as_float(u.y & 0xffff0000u);
    acc[4] += d * __uint_as_float(u.z << 16);
    acc[5] += d * __uint_as_float(u.z & 0xffff0000u);
    acc[6] += d * __uint_as_float(u.w << 16);
    acc[7] += d * __uint_as_float(u.w & 0xffff0000u);
}

template <bool FINAL>
__global__ __launch_bounds__(256) void k_agg(const uint4* __restrict__ h4,
                                             const int* __restrict__ offsets,
                                             const int* __restrict__ csr_src,
                                             const float* __restrict__ dinv,
                                             const float* __restrict__ bias,
                                             const float* __restrict__ Wlin,
                                             const float* __restrict__ blin,
                                             float* __restrict__ aggout) {
    int wave = (blockIdx.x * 256 + threadIdx.x) >> 6;
    int lane = threadIdx.x & 63;
    if (wave >= N_NODES) return;
    int n = wave;
    int o0 = offsets[n], o1 = offsets[n + 1];
    float dv = dinv[n];
    int eg = lane >> 4, cq = lane & 15;

    float acc[8];
#pragma unroll
    for (int j = 0; j < 8; ++j) acc[j] = 0.f;

    int e = o0;
    // alignment prologue: if o0 odd, group 0 handles one edge
    if (e < o1 && (e & 1)) {
        if (eg == 0) {
            int s = csr_src[e];
            accum8(acc, dinv[s], h4[s * 16 + cq]);
        }
        ++e;
    }
    // main: 8 edges per iteration (2 per lane via int2)
    for (; e + 8 <= o1; e += 8) {
        int2 ss = *(const int2*)(csr_src + e + 2 * eg);
        float d0 = dinv[ss.x];
        float d1 = dinv[ss.y];
        uint4 u0 = h4[ss.x * 16 + cq];
        uint4 u1 = h4[ss.y * 16 + cq];
        accum8(acc, d0, u0);
        accum8(acc, d1, u1);
    }
    // tail: r in [0,8), group eg takes edges e+2eg, e+2eg+1 if in range
    {
        int r = o1 - e;
        int b0 = e + 2 * eg;
        if (2 * eg < r) {
            int s = csr_src[b0];
            accum8(acc, dinv[s], h4[s * 16 + cq]);
        }
        if (2 * eg + 1 < r) {
            int s = csr_src[b0 + 1];
            accum8(acc, dinv[s], h4[s * 16 + cq]);
        }
    }
    // combine the 4 edge-groups
#pragma unroll
    for (int j = 0; j < 8; ++j) {
        acc[j] += __shfl_xor(acc[j], 16, 64);
        acc[j] += __shfl_xor(acc[j], 32, 64);
    }
    // self-loop + bias
    uint4 us = h4[n * 16 + cq];
    float hv[8];
    hv[0] = __uint_as_float(us.x << 16); hv[1] = __uint_as_float(us.x & 0xffff0000u);
    hv[2] = __uint_as_float(us.y << 16); hv[3] = __uint_as_float(us.y & 0xffff0000u);
    hv[4] = __uint_as_float(us.z << 16); hv[5] = __uint_as_float(us.z & 0xffff0000u);
    hv[6] = __uint_as_float(us.w << 16); hv[7] = __uint_as_float(us.w & 0xffff0000u);
    float4 bv0 = ((const float4*)bias)[cq * 2];
    float4 bv1 = ((const float4*)bias)[cq * 2 + 1];
    float o[8];
    float dv2 = dv * dv;
    o[0] = dv * acc[0] + dv2 * hv[0] + bv0.x;
    o[1] = dv * acc[1] + dv2 * hv[1] + bv0.y;
    o[2] = dv * acc[2] + dv2 * hv[2] + bv0.z;
    o[3] = dv * acc[3] + dv2 * hv[3] + bv0.w;
    o[4] = dv * acc[4] + dv2 * hv[4] + bv1.x;
    o[5] = dv * acc[5] + dv2 * hv[5] + bv1.y;
    o[6] = dv * acc[6] + dv2 * hv[6] + bv1.z;
    o[7] = dv * acc[7] + dv2 * hv[7] + bv1.w;

    if (!FINAL) {
        if (eg == 0) {
            float4* out4 = (float4*)aggout;
            out4[n * 32 + cq * 2]     = make_float4(o[0], o[1], o[2], o[3]);
            out4[n * 32 + cq * 2 + 1] = make_float4(o[4], o[5], o[6], o[7]);
        }
    } else {
        float4 wl0 = ((const float4*)Wlin)[cq * 2];
        float4 wl1 = ((const float4*)Wlin)[cq * 2 + 1];
        float v = fmaxf(o[0], 0.f) * wl0.x + fmaxf(o[1], 0.f) * wl0.y
                + fmaxf(o[2], 0.f) * wl0.z + fmaxf(o[3], 0.f) * wl0.w
                + fmaxf(o[4], 0.f) * wl1.x + fmaxf(o[5], 0.f) * wl1.y
                + fmaxf(o[6], 0.f) * wl1.z + fmaxf(o[7], 0.f) * wl1.w;
        v += __shfl_xor(v, 1, 64);
        v += __shfl_xor(v, 2, 64);
        v += __shfl_xor(v, 4, 64);
        v += __shfl_xor(v, 8, 64);
        if (lane == 0) aggout[n] = v + blin[0];
    }
}

// ---------------------------------------------------------------------------
extern "C" void kernel_launch(void* const* d_in, const int* in_sizes, int n_in,
                              void* d_out, int out_size, void* d_ws, size_t ws_size,
                              hipStream_t stream) {
    const float* x    = (const float*)d_in[0];
    const int*   ei   = (const int*)d_in[2];
    const float* W1   = (const float*)d_in[4];
    const float* b1   = (const float*)d_in[5];
    const float* W2   = (const float*)d_in[6];
    const float* b2   = (const float*)d_in[7];
    const float* Wlin = (const float*)d_in[8];
    const float* blin = (const float*)d_in[9];
    float* out = (float*)d_out;

    char* ws = (char*)d_ws;
    size_t off = 0;
    auto carve = [&](size_t bytes) -> void* {
        void* p = ws + off;
        off = (off + bytes + 255) & ~(size_t)255;
        return p;
    };
    int*   gcur    = (int*)  carve(NBA * sizeof(int));
    int*   gbase   = (int*)  carve(NBA * sizeof(int));
    int*   offsets = (int*)  carve((N_NODES + 1) * sizeof(int));
    float* dinv    = (float*)carve(N_NODES * sizeof(float));
    int2*  tmp     = (int2*) carve((size_t)NBA * CAPA * sizeof(int2));   // 7.5 MB
    int*   csr_src = (int*)  carve(N_EDGES * sizeof(int));
    unsigned int* hbf = (unsigned int*)carve((size_t)N_NODES * 64 * sizeof(unsigned int));
    float* agg     = (float*)carve((size_t)N_NODES * C * sizeof(float));

    const int NB_A = (N_EDGES + CHUNK - 1) / CHUNK;   // 391
    const int NB_G = (N_NODES + 63) / 64;             // 782
    const int NB_W = (N_NODES + 3) / 4;               // 12500

    hipMemsetAsync(gcur, 0, NBA * sizeof(int), stream);

    // CSR build: 2-level radix partition (no per-node global atomics)
    k_binA<<<NB_A, 256, 0, stream>>>(ei, gcur, tmp);
    k_scanA<<<1, 256, 0, stream>>>(gcur, gbase, offsets);
    k_binB<<<NBA, 256, 0, stream>>>(tmp, gcur, gbase, csr_src, offsets, dinv);

    // Layer 1
    k_gemm<false><<<NB_G, 256, 0, stream>>>(x, W1, hbf);
    k_agg<false><<<NB_W, 256, 0, stream>>>((const uint4*)hbf, offsets, csr_src, dinv,
                                           b1, Wlin, blin, agg);
    // Layer 2
    k_gemm<true><<<NB_G, 256, 0, stream>>>(agg, W2, hbf);
    k_agg<true><<<NB_W, 256, 0, stream>>>((const uint4*)hbf, offsets, csr_src, dinv,
                                          b2, Wlin, blin, out);
}